// Round 1
// baseline (246.479 us; speedup 1.0000x reference)
//
#include <hip/hip_runtime.h>

typedef unsigned short USH;
typedef __bf16 v8bf __attribute__((ext_vector_type(8)));
typedef float v4f __attribute__((ext_vector_type(4)));
typedef unsigned short us8 __attribute__((ext_vector_type(8)));

#define SB 2048
#define DD 2048
#define NH 16
#define DPH 128

__device__ __forceinline__ USH f2bf(float f) {
  unsigned u = __float_as_uint(f);
  u = u + 0x7fffu + ((u >> 16) & 1u);
  return (USH)(u >> 16);
}

// ---- transpose + convert weights: wt[j][k] = bf16(w[k][j]) ----
__global__ __launch_bounds__(256) void k_transw(const float* __restrict__ wq,
    const float* __restrict__ wk, USH* __restrict__ wqt, USH* __restrict__ wkt) {
  __shared__ USH tl[64][72];
  const float* w = blockIdx.z ? wk : wq;
  USH* wt = blockIdx.z ? wkt : wqt;
  const int k0 = blockIdx.y * 64, j0 = blockIdx.x * 64;
  const int t = threadIdx.x;
#pragma unroll
  for (int p = 0; p < 4; ++p) {
    const int r = p * 16 + (t >> 4);
    const int c = (t & 15) * 4;
    const float4 v = *(const float4*)&w[(size_t)(k0 + r) * DD + j0 + c];
    tl[c + 0][r] = f2bf(v.x);
    tl[c + 1][r] = f2bf(v.y);
    tl[c + 2][r] = f2bf(v.z);
    tl[c + 3][r] = f2bf(v.w);
  }
  __syncthreads();
#pragma unroll
  for (int p = 0; p < 2; ++p) {
    const int j = p * 32 + (t >> 3);
    const int seg = (t & 7) * 8;
    us8 v = *(const us8*)&tl[j][seg];
    *(us8*)&wt[(size_t)(j0 + j) * DD + k0 + seg] = v;
  }
}

// ---- wvo[d][h] = sum_dp wv[d][h*128+dp]*wo[h*128+dp]; block 2048 does bvo ----
__global__ __launch_bounds__(256) void k_wvo(const float* __restrict__ wvf,
    const float* __restrict__ bvf, const float* __restrict__ wo,
    float* __restrict__ wvo, float* __restrict__ bvo) {
  __shared__ float red[256];
  const int t = threadIdx.x;
  const int d = blockIdx.x;
  const float* src = (d == DD) ? bvf : (wvf + (size_t)d * DD);
  const float4 a0 = *(const float4*)&src[t * 8];
  const float4 a1 = *(const float4*)&src[t * 8 + 4];
  const float4 w0 = *(const float4*)&wo[t * 8];
  const float4 w1 = *(const float4*)&wo[t * 8 + 4];
  red[t] = a0.x * w0.x + a0.y * w0.y + a0.z * w0.z + a0.w * w0.w +
           a1.x * w1.x + a1.y * w1.y + a1.z * w1.z + a1.w * w1.w;
  __syncthreads();
  for (int s = 8; s > 0; s >>= 1) {
    if ((t & 15) < s) red[t] += red[t + s];
    __syncthreads();
  }
  if ((t & 15) == 0) {
    float* dst = (d == DD) ? bvo : (wvo + d * NH);
    dst[t >> 4] = red[t];
  }
}

// ---- vw[b][h][s] = x[b,s,:]@wvo[:,h] + bvo[h]  (fp32, 8 rows per block) ----
__global__ __launch_bounds__(256) void k_vw(const float* __restrict__ x,
    const float* __restrict__ wvo, const float* __restrict__ bvo,
    float* __restrict__ vw) {
  __shared__ float xs[8][2048];
  __shared__ float red[16][16 * 9];
  const int t = threadIdx.x;
  const int row0 = blockIdx.x * 8;
  for (int r = 0; r < 8; ++r)
    for (int i = t; i < 2048; i += 256)
      xs[r][i] = x[(size_t)(row0 + r) * DD + i];
  __syncthreads();
  const int h = t & 15, jg = t >> 4;
  float acc[8];
#pragma unroll
  for (int r = 0; r < 8; ++r) acc[r] = 0.f;
  for (int ii = 0; ii < 128; ++ii) {
    const int d = jg + ii * 16;
    const float wv_ = wvo[d * NH + h];
#pragma unroll
    for (int r = 0; r < 8; ++r) acc[r] += xs[r][d] * wv_;
  }
#pragma unroll
  for (int r = 0; r < 8; ++r) red[jg][h * 9 + r] = acc[r];
  __syncthreads();
  for (int s = 8; s > 0; s >>= 1) {
    if (jg < s) {
#pragma unroll
      for (int r = 0; r < 8; ++r) red[jg][h * 9 + r] += red[jg + s][h * 9 + r];
    }
    __syncthreads();
  }
  if (jg == 0) {
    const float bb = bvo[h];
#pragma unroll
    for (int r = 0; r < 8; ++r) {
      const int row = row0 + r;
      vw[((size_t)(row >> 11) * NH + h) * SB + (row & 2047)] = red[0][h * 9 + r] + bb;
    }
  }
}

// ---- projection GEMM: C = x @ W (+bias) -> bf16 [B][H][S][128]; z=0:Q(scaled), z=1:K ----
__global__ __launch_bounds__(256) void k_gemm(const float* __restrict__ x,
    const USH* __restrict__ wqt, const USH* __restrict__ wkt,
    const float* __restrict__ bq, const float* __restrict__ bk,
    USH* __restrict__ Qb, USH* __restrict__ Kb) {
  __shared__ USH As[128 * 32];
  __shared__ USH Bs[128 * 32];
  const int z = blockIdx.z;
  const USH* wt = z ? wkt : wqt;
  const float* bias = z ? bk : bq;
  USH* outp = z ? Kb : Qb;
  const float qscale = z ? 1.0f : 0.08838834764831845f;
  const int row0 = blockIdx.y * 128, col0 = blockIdx.x * 128;
  const int t = threadIdx.x;
  const int w = t >> 6, lane = t & 63;
  const int lr = lane & 15, g = lane >> 4;
  const int mrow = (w >> 1) * 64, ncol = (w & 1) * 64;
  // A staging: 4 threads/row (fp32 -> bf16), 2 passes of 64 rows
  const int ar = t >> 2, aq = t & 3;
  // B staging: 2 threads/row (bf16), 128 rows
  const int br = t >> 1, bhf = t & 1;
  const int rdoff = (g ^ (lr & 3)) * 8;

  v4f acc[4][4];
#pragma unroll
  for (int i = 0; i < 4; ++i)
#pragma unroll
    for (int j = 0; j < 4; ++j) acc[i][j] = (v4f){0.f, 0.f, 0.f, 0.f};

  for (int kt = 0; kt < DD / 32; ++kt) {
    const int k0 = kt * 32;
    // stage A (x fp32 -> bf16)
#pragma unroll
    for (int p = 0; p < 2; ++p) {
      const int r = ar + p * 64;
      const float4 va = *(const float4*)&x[(size_t)(row0 + r) * DD + k0 + aq * 8];
      const float4 vb = *(const float4*)&x[(size_t)(row0 + r) * DD + k0 + aq * 8 + 4];
      us8 o;
      o[0] = f2bf(va.x); o[1] = f2bf(va.y); o[2] = f2bf(va.z); o[3] = f2bf(va.w);
      o[4] = f2bf(vb.x); o[5] = f2bf(vb.y); o[6] = f2bf(vb.z); o[7] = f2bf(vb.w);
      *(us8*)&As[r * 32 + ((aq ^ (r & 3)) * 8)] = o;
    }
    // stage B (bf16 pre-transposed)
    {
      const USH* srcB = wt + (size_t)(col0 + br) * DD + k0 + bhf * 16;
      us8 b0 = *(const us8*)srcB;
      us8 b1 = *(const us8*)(srcB + 8);
      *(us8*)&Bs[br * 32 + (((bhf * 2 + 0) ^ (br & 3)) * 8)] = b0;
      *(us8*)&Bs[br * 32 + (((bhf * 2 + 1) ^ (br & 3)) * 8)] = b1;
    }
    __syncthreads();
    v8bf af[4], bfr[4];
#pragma unroll
    for (int mi = 0; mi < 4; ++mi)
      af[mi] = *(const v8bf*)&As[(mrow + mi * 16 + lr) * 32 + rdoff];
#pragma unroll
    for (int ni = 0; ni < 4; ++ni)
      bfr[ni] = *(const v8bf*)&Bs[(ncol + ni * 16 + lr) * 32 + rdoff];
#pragma unroll
    for (int mi = 0; mi < 4; ++mi)
#pragma unroll
      for (int ni = 0; ni < 4; ++ni)
        acc[mi][ni] = __builtin_amdgcn_mfma_f32_16x16x32_bf16(af[mi], bfr[ni], acc[mi][ni], 0, 0, 0);
    __syncthreads();
  }
  // epilogue: +bias, (scale), -> bf16 [B][H][S][DPH]
#pragma unroll
  for (int ni = 0; ni < 4; ++ni) {
    const int col = col0 + ncol + ni * 16 + lr;
    const float bv_ = bias[col];
    const int hh = col >> 7, dp = col & 127;
#pragma unroll
    for (int mi = 0; mi < 4; ++mi) {
#pragma unroll
      for (int r = 0; r < 4; ++r) {
        const int row = row0 + mrow + mi * 16 + g * 4 + r;
        const int bi = row >> 11, s = row & 2047;
        const float v = (acc[mi][ni][r] + bv_) * qscale;
        outp[(((size_t)bi * NH + hh) * SB + s) * DPH + dp] = f2bf(v);
      }
    }
  }
}

// ---- attention: per wave 16 q-rows; K tiles of 16; online softmax; scalar "V" ----
__global__ __launch_bounds__(256) void k_attn(const USH* __restrict__ Qb,
    const USH* __restrict__ Kb, const float* __restrict__ vw,
    float* __restrict__ part) {
  const int bh = blockIdx.y;
  const int wid = threadIdx.x >> 6;
  const int lane = threadIdx.x & 63;
  const int lr = lane & 15, g = lane >> 4;
  const int qb = blockIdx.x * 64 + wid * 16;
  const USH* Qp = Qb + (size_t)bh * SB * DPH;
  const USH* Kp = Kb + (size_t)bh * SB * DPH;
  const float* vwp = vw + (size_t)bh * SB;

  v8bf qf[4];
  {
    const USH* qrp = Qp + (size_t)(qb + lr) * DPH + g * 8;
#pragma unroll
    for (int kc = 0; kc < 4; ++kc) qf[kc] = *(const v8bf*)(qrp + kc * 32);
  }
  float m[4], ls[4], os[4];
#pragma unroll
  for (int r = 0; r < 4; ++r) { m[r] = -1e30f; ls[r] = 0.f; os[r] = 0.f; }

  const int kb0 = qb > 511 ? ((qb - 511) & ~15) : 0;
  for (int kb = kb0; kb <= qb + 15; kb += 16) {
    v4f acc = (v4f){0.f, 0.f, 0.f, 0.f};
    const USH* krp = Kp + (size_t)(kb + lr) * DPH + g * 8;
    v8bf k0 = *(const v8bf*)(krp);
    v8bf k1 = *(const v8bf*)(krp + 32);
    v8bf k2 = *(const v8bf*)(krp + 64);
    v8bf k3 = *(const v8bf*)(krp + 96);
    acc = __builtin_amdgcn_mfma_f32_16x16x32_bf16(qf[0], k0, acc, 0, 0, 0);
    acc = __builtin_amdgcn_mfma_f32_16x16x32_bf16(qf[1], k1, acc, 0, 0, 0);
    acc = __builtin_amdgcn_mfma_f32_16x16x32_bf16(qf[2], k2, acc, 0, 0, 0);
    acc = __builtin_amdgcn_mfma_f32_16x16x32_bf16(qf[3], k3, acc, 0, 0, 0);
    const int k_i = kb + lr;
    const float vv = vwp[k_i];
#pragma unroll
    for (int r = 0; r < 4; ++r) {
      const int q_i = qb + g * 4 + r;
      float s = acc[r];
      const bool valid = (k_i <= q_i) && (q_i - k_i < 512);
      s = valid ? s : -1e30f;
      float rm = s;
      rm = fmaxf(rm, __shfl_xor(rm, 1));
      rm = fmaxf(rm, __shfl_xor(rm, 2));
      rm = fmaxf(rm, __shfl_xor(rm, 4));
      rm = fmaxf(rm, __shfl_xor(rm, 8));
      const float mn = fmaxf(m[r], rm);
      const float al = __expf(m[r] - mn);
      const float p = __expf(s - mn);
      ls[r] = ls[r] * al + p;
      os[r] = os[r] * al + p * vv;
      m[r] = mn;
    }
  }
#pragma unroll
  for (int r = 0; r < 4; ++r) {
    os[r] += __shfl_xor(os[r], 1); ls[r] += __shfl_xor(ls[r], 1);
    os[r] += __shfl_xor(os[r], 2); ls[r] += __shfl_xor(ls[r], 2);
    os[r] += __shfl_xor(os[r], 4); ls[r] += __shfl_xor(ls[r], 4);
    os[r] += __shfl_xor(os[r], 8); ls[r] += __shfl_xor(ls[r], 8);
  }
  if (lr == 0) {
#pragma unroll
    for (int r = 0; r < 4; ++r)
      part[(size_t)bh * SB + qb + g * 4 + r] = os[r] / ls[r];
  }
}

// ---- final: out[b,s] = bo + sum_h part[b,h,s] ----
__global__ __launch_bounds__(256) void k_final(const float* __restrict__ part,
    const float* __restrict__ bo, float* __restrict__ out) {
  const int i = blockIdx.x * 256 + threadIdx.x;
  const int b = i >> 11, s = i & 2047;
  float acc = bo[0];
#pragma unroll
  for (int h = 0; h < NH; ++h) acc += part[(size_t)(b * NH + h) * SB + s];
  out[i] = acc;
}

extern "C" void kernel_launch(void* const* d_in, const int* in_sizes, int n_in,
                              void* d_out, int out_size, void* d_ws, size_t ws_size,
                              hipStream_t stream) {
  const float* x   = (const float*)d_in[0];
  const float* wq  = (const float*)d_in[1];
  const float* bq  = (const float*)d_in[2];
  const float* wk  = (const float*)d_in[3];
  const float* bk  = (const float*)d_in[4];
  const float* wvf = (const float*)d_in[5];
  const float* bvf = (const float*)d_in[6];
  const float* wo  = (const float*)d_in[7];
  const float* bo  = (const float*)d_in[8];
  float* out = (float*)d_out;
  char* ws = (char*)d_ws;

  USH*   wqt = (USH*)(ws);
  USH*   wkt = (USH*)(ws + 8388608);
  USH*   Qb  = (USH*)(ws + 16777216);
  USH*   Kb  = (USH*)(ws + 33554432);
  float* vw  = (float*)(ws + 50331648);
  float* wvo = (float*)(ws + 50593792);
  float* bvo = (float*)(ws + 50724864);
  float* part= (float*)(ws + 50725120);

  k_transw<<<dim3(32, 32, 2), dim3(256), 0, stream>>>(wq, wk, wqt, wkt);
  k_wvo<<<dim3(2049), dim3(256), 0, stream>>>(wvf, bvf, wo, wvo, bvo);
  k_vw<<<dim3(512), dim3(256), 0, stream>>>(x, wvo, bvo, vw);
  k_gemm<<<dim3(16, 32, 2), dim3(256), 0, stream>>>(x, wqt, wkt, bq, bk, Qb, Kb);
  k_attn<<<dim3(32, 32), dim3(256), 0, stream>>>(Qb, Kb, vw, part);
  k_final<<<dim3(16), dim3(256), 0, stream>>>(part, bo, out);
}

// Round 2
// 202.204 us; speedup vs baseline: 1.2190x; 1.2190x over previous
//
#include <hip/hip_runtime.h>

typedef unsigned short USH;
typedef __bf16 v8bf __attribute__((ext_vector_type(8)));
typedef float v4f __attribute__((ext_vector_type(4)));
typedef unsigned short us8 __attribute__((ext_vector_type(8)));

#define SB 2048
#define DD 2048
#define NH 16
#define DPH 128

__device__ __forceinline__ USH f2bf(float f) {
  unsigned u = __float_as_uint(f);
  u = u + 0x7fffu + ((u >> 16) & 1u);
  return (USH)(u >> 16);
}

__device__ __forceinline__ void gl16(const USH* g, USH* l) {
  __builtin_amdgcn_global_load_lds(
      (const __attribute__((address_space(1))) void*)(g),
      (__attribute__((address_space(3))) void*)(l), 16, 0, 0);
}

// ---- x (fp32) -> bf16, flat ----
__global__ __launch_bounds__(256) void k_xbf(const float* __restrict__ x,
                                             USH* __restrict__ xb) {
  const int i = (blockIdx.x * 256 + threadIdx.x) * 8;
  const float4 a = *(const float4*)&x[i];
  const float4 b = *(const float4*)&x[i + 4];
  v8bf o;
  o[0] = (__bf16)a.x; o[1] = (__bf16)a.y; o[2] = (__bf16)a.z; o[3] = (__bf16)a.w;
  o[4] = (__bf16)b.x; o[5] = (__bf16)b.y; o[6] = (__bf16)b.z; o[7] = (__bf16)b.w;
  *(v8bf*)&xb[i] = o;
}

// ---- transpose + convert weights: wt[j][k] = bf16(w[k][j]) ----
__global__ __launch_bounds__(256) void k_transw(const float* __restrict__ wq,
    const float* __restrict__ wk, USH* __restrict__ wqt, USH* __restrict__ wkt) {
  __shared__ USH tl[64][72];
  const float* w = blockIdx.z ? wk : wq;
  USH* wt = blockIdx.z ? wkt : wqt;
  const int k0 = blockIdx.y * 64, j0 = blockIdx.x * 64;
  const int t = threadIdx.x;
#pragma unroll
  for (int p = 0; p < 4; ++p) {
    const int r = p * 16 + (t >> 4);
    const int c = (t & 15) * 4;
    const float4 v = *(const float4*)&w[(size_t)(k0 + r) * DD + j0 + c];
    tl[c + 0][r] = f2bf(v.x);
    tl[c + 1][r] = f2bf(v.y);
    tl[c + 2][r] = f2bf(v.z);
    tl[c + 3][r] = f2bf(v.w);
  }
  __syncthreads();
#pragma unroll
  for (int p = 0; p < 2; ++p) {
    const int j = p * 32 + (t >> 3);
    const int seg = (t & 7) * 8;
    us8 v = *(const us8*)&tl[j][seg];
    *(us8*)&wt[(size_t)(j0 + j) * DD + k0 + seg] = v;
  }
}

// ---- wvo[d][h] = sum_dp wv[d][h*128+dp]*wo[h*128+dp]; block 2048 does bvo ----
__global__ __launch_bounds__(256) void k_wvo(const float* __restrict__ wvf,
    const float* __restrict__ bvf, const float* __restrict__ wo,
    float* __restrict__ wvo, float* __restrict__ bvo) {
  __shared__ float red[256];
  const int t = threadIdx.x;
  const int d = blockIdx.x;
  const float* src = (d == DD) ? bvf : (wvf + (size_t)d * DD);
  const float4 a0 = *(const float4*)&src[t * 8];
  const float4 a1 = *(const float4*)&src[t * 8 + 4];
  const float4 w0 = *(const float4*)&wo[t * 8];
  const float4 w1 = *(const float4*)&wo[t * 8 + 4];
  red[t] = a0.x * w0.x + a0.y * w0.y + a0.z * w0.z + a0.w * w0.w +
           a1.x * w1.x + a1.y * w1.y + a1.z * w1.z + a1.w * w1.w;
  __syncthreads();
  for (int s = 8; s > 0; s >>= 1) {
    if ((t & 15) < s) red[t] += red[t + s];
    __syncthreads();
  }
  if ((t & 15) == 0) {
    float* dst = (d == DD) ? bvo : (wvo + d * NH);
    dst[t >> 4] = red[t];
  }
}

// ---- vw[b][h][s] = x[b,s,:]@wvo[:,h] + bvo[h]  (fp32, 8 rows per block) ----
__global__ __launch_bounds__(256) void k_vw(const float* __restrict__ x,
    const float* __restrict__ wvo, const float* __restrict__ bvo,
    float* __restrict__ vw) {
  __shared__ float xs[8][2048];
  __shared__ float red[16][16 * 9];
  const int t = threadIdx.x;
  const int row0 = blockIdx.x * 8;
  for (int r = 0; r < 8; ++r)
    for (int i = t; i < 2048; i += 256)
      xs[r][i] = x[(size_t)(row0 + r) * DD + i];
  __syncthreads();
  const int h = t & 15, jg = t >> 4;
  float acc[8];
#pragma unroll
  for (int r = 0; r < 8; ++r) acc[r] = 0.f;
  for (int ii = 0; ii < 128; ++ii) {
    const int d = jg + ii * 16;
    const float wv_ = wvo[d * NH + h];
#pragma unroll
    for (int r = 0; r < 8; ++r) acc[r] += xs[r][d] * wv_;
  }
#pragma unroll
  for (int r = 0; r < 8; ++r) red[jg][h * 9 + r] = acc[r];
  __syncthreads();
  for (int s = 8; s > 0; s >>= 1) {
    if (jg < s) {
#pragma unroll
      for (int r = 0; r < 8; ++r) red[jg][h * 9 + r] += red[jg + s][h * 9 + r];
    }
    __syncthreads();
  }
  if (jg == 0) {
    const float bb = bvo[h];
#pragma unroll
    for (int r = 0; r < 8; ++r) {
      const int row = row0 + r;
      vw[((size_t)(row >> 11) * NH + h) * SB + (row & 2047)] = red[0][h * 9 + r] + bb;
    }
  }
}

// ---- projection GEMM: C = x @ W (+bias) -> bf16 [B][H][S][128]; z=0:Q(scaled), z=1:K
// FAST: A from pre-converted bf16 x via global_load_lds (pre-swizzled source).
// !FAST: A reg-staged from fp32 x with cvt_pk-able casts. B always global_load_lds.
template <bool FAST>
__global__ __launch_bounds__(256) void k_gemm(const float* __restrict__ x,
    const USH* __restrict__ xb,
    const USH* __restrict__ wqt, const USH* __restrict__ wkt,
    const float* __restrict__ bq, const float* __restrict__ bk,
    USH* __restrict__ Qb, USH* __restrict__ Kb) {
  __shared__ USH As[128 * 32];
  __shared__ USH Bs[128 * 32];
  const int z = blockIdx.z;
  const USH* wt = z ? wkt : wqt;
  const float* bias = z ? bk : bq;
  USH* outp = z ? Kb : Qb;
  const float qscale = z ? 1.0f : 0.08838834764831845f;
  // XCD-bijective swizzle: 512 blocks per z, 8 XCDs, 64 per XCD chunk
  const int bid = blockIdx.y * 16 + blockIdx.x;
  const int swz = (bid & 7) * 64 + (bid >> 3);
  const int row0 = (swz >> 4) * 128, col0 = (swz & 15) * 128;
  const int t = threadIdx.x;
  const int wv = t >> 6, lane = t & 63;
  const int lr = lane & 15, g = lane >> 4;
  const int mrow = (wv >> 1) * 64, ncol = (wv & 1) * 64;
  // chunk ids (16B each) for global_load_lds staging: 512 chunks per matrix
  const int c0 = wv * 128 + lane;
  const int c1 = c0 + 64;
  const int r0c = c0 >> 2, s0c = c0 & 3;
  const int r1c = c1 >> 2, s1c = c1 & 3;
  const size_t aoff0 = (size_t)(row0 + r0c) * DD + (size_t)((s0c ^ (r0c & 3)) * 8);
  const size_t aoff1 = (size_t)(row0 + r1c) * DD + (size_t)((s1c ^ (r1c & 3)) * 8);
  const size_t boff0 = (size_t)(col0 + r0c) * DD + (size_t)((s0c ^ (r0c & 3)) * 8);
  const size_t boff1 = (size_t)(col0 + r1c) * DD + (size_t)((s1c ^ (r1c & 3)) * 8);
  USH* lA0 = &As[c0 * 8];
  USH* lA1 = &As[c1 * 8];
  USH* lB0 = &Bs[c0 * 8];
  USH* lB1 = &Bs[c1 * 8];
  // reg-staged A params (fallback)
  const int ar = t >> 2, aq = t & 3;
  const int rdoff = (g ^ (lr & 3)) * 8;

  v4f acc[4][4];
#pragma unroll
  for (int i = 0; i < 4; ++i)
#pragma unroll
    for (int j = 0; j < 4; ++j) acc[i][j] = (v4f){0.f, 0.f, 0.f, 0.f};

  for (int kt = 0; kt < DD / 32; ++kt) {
    const int k0 = kt * 32;
    if constexpr (FAST) {
      gl16(xb + aoff0 + k0, lA0);
      gl16(xb + aoff1 + k0, lA1);
    } else {
#pragma unroll
      for (int p = 0; p < 2; ++p) {
        const int r = ar + p * 64;
        const float4 va = *(const float4*)&x[(size_t)(row0 + r) * DD + k0 + aq * 8];
        const float4 vb2 = *(const float4*)&x[(size_t)(row0 + r) * DD + k0 + aq * 8 + 4];
        v8bf o;
        o[0] = (__bf16)va.x;  o[1] = (__bf16)va.y;  o[2] = (__bf16)va.z;  o[3] = (__bf16)va.w;
        o[4] = (__bf16)vb2.x; o[5] = (__bf16)vb2.y; o[6] = (__bf16)vb2.z; o[7] = (__bf16)vb2.w;
        *(v8bf*)&As[r * 32 + ((aq ^ (r & 3)) * 8)] = o;
      }
    }
    gl16(wt + boff0 + k0, lB0);
    gl16(wt + boff1 + k0, lB1);
    __syncthreads();
    v8bf af[4], bfr[4];
#pragma unroll
    for (int mi = 0; mi < 4; ++mi)
      af[mi] = *(const v8bf*)&As[(mrow + mi * 16 + lr) * 32 + rdoff];
#pragma unroll
    for (int ni = 0; ni < 4; ++ni)
      bfr[ni] = *(const v8bf*)&Bs[(ncol + ni * 16 + lr) * 32 + rdoff];
#pragma unroll
    for (int mi = 0; mi < 4; ++mi)
#pragma unroll
      for (int ni = 0; ni < 4; ++ni)
        acc[mi][ni] = __builtin_amdgcn_mfma_f32_16x16x32_bf16(af[mi], bfr[ni], acc[mi][ni], 0, 0, 0);
    __syncthreads();
  }
  // epilogue: +bias, (scale), -> bf16 [B][H][S][DPH]
#pragma unroll
  for (int ni = 0; ni < 4; ++ni) {
    const int col = col0 + ncol + ni * 16 + lr;
    const float bv_ = bias[col];
    const int hh = col >> 7, dp = col & 127;
#pragma unroll
    for (int mi = 0; mi < 4; ++mi) {
#pragma unroll
      for (int r = 0; r < 4; ++r) {
        const int row = row0 + mrow + mi * 16 + g * 4 + r;
        const int bi = row >> 11, s = row & 2047;
        const float v = (acc[mi][ni][r] + bv_) * qscale;
        outp[(((size_t)bi * NH + hh) * SB + s) * DPH + dp] = f2bf(v);
      }
    }
  }
}

// ---- attention: per wave 16 q-rows; K tiles of 16; online softmax; scalar "V" ----
__global__ __launch_bounds__(256) void k_attn(const USH* __restrict__ Qb,
    const USH* __restrict__ Kb, const float* __restrict__ vw,
    float* __restrict__ part) {
  const int bh = blockIdx.y;
  const int wid = threadIdx.x >> 6;
  const int lane = threadIdx.x & 63;
  const int lr = lane & 15, g = lane >> 4;
  const int qb = blockIdx.x * 64 + wid * 16;
  const USH* Qp = Qb + (size_t)bh * SB * DPH;
  const USH* Kp = Kb + (size_t)bh * SB * DPH;
  const float* vwp = vw + (size_t)bh * SB;

  v8bf qf[4];
  {
    const USH* qrp = Qp + (size_t)(qb + lr) * DPH + g * 8;
#pragma unroll
    for (int kc = 0; kc < 4; ++kc) qf[kc] = *(const v8bf*)(qrp + kc * 32);
  }
  float m[4], ls[4], os[4];
#pragma unroll
  for (int r = 0; r < 4; ++r) { m[r] = -1e30f; ls[r] = 0.f; os[r] = 0.f; }

  const int kb0 = qb > 511 ? ((qb - 511) & ~15) : 0;
  for (int kb = kb0; kb <= qb + 15; kb += 16) {
    v4f acc = (v4f){0.f, 0.f, 0.f, 0.f};
    const USH* krp = Kp + (size_t)(kb + lr) * DPH + g * 8;
    v8bf k0 = *(const v8bf*)(krp);
    v8bf k1 = *(const v8bf*)(krp + 32);
    v8bf k2 = *(const v8bf*)(krp + 64);
    v8bf k3 = *(const v8bf*)(krp + 96);
    acc = __builtin_amdgcn_mfma_f32_16x16x32_bf16(qf[0], k0, acc, 0, 0, 0);
    acc = __builtin_amdgcn_mfma_f32_16x16x32_bf16(qf[1], k1, acc, 0, 0, 0);
    acc = __builtin_amdgcn_mfma_f32_16x16x32_bf16(qf[2], k2, acc, 0, 0, 0);
    acc = __builtin_amdgcn_mfma_f32_16x16x32_bf16(qf[3], k3, acc, 0, 0, 0);
    const int k_i = kb + lr;
    const float vv = vwp[k_i];
#pragma unroll
    for (int r = 0; r < 4; ++r) {
      const int q_i = qb + g * 4 + r;
      float s = acc[r];
      const bool valid = (k_i <= q_i) && (q_i - k_i < 512);
      s = valid ? s : -1e30f;
      float rm = s;
      rm = fmaxf(rm, __shfl_xor(rm, 1));
      rm = fmaxf(rm, __shfl_xor(rm, 2));
      rm = fmaxf(rm, __shfl_xor(rm, 4));
      rm = fmaxf(rm, __shfl_xor(rm, 8));
      const float mn = fmaxf(m[r], rm);
      const float al = __expf(m[r] - mn);
      const float p = __expf(s - mn);
      ls[r] = ls[r] * al + p;
      os[r] = os[r] * al + p * vv;
      m[r] = mn;
    }
  }
#pragma unroll
  for (int r = 0; r < 4; ++r) {
    os[r] += __shfl_xor(os[r], 1); ls[r] += __shfl_xor(ls[r], 1);
    os[r] += __shfl_xor(os[r], 2); ls[r] += __shfl_xor(ls[r], 2);
    os[r] += __shfl_xor(os[r], 4); ls[r] += __shfl_xor(ls[r], 4);
    os[r] += __shfl_xor(os[r], 8); ls[r] += __shfl_xor(ls[r], 8);
  }
  if (lr == 0) {
#pragma unroll
    for (int r = 0; r < 4; ++r)
      part[(size_t)bh * SB + qb + g * 4 + r] = os[r] / ls[r];
  }
}

// ---- final: out[b,s] = bo + sum_h part[b,h,s] ----
__global__ __launch_bounds__(256) void k_final(const float* __restrict__ part,
    const float* __restrict__ bo, float* __restrict__ out) {
  const int i = blockIdx.x * 256 + threadIdx.x;
  const int b = i >> 11, s = i & 2047;
  float acc = bo[0];
#pragma unroll
  for (int h = 0; h < NH; ++h) acc += part[(size_t)(b * NH + h) * SB + s];
  out[i] = acc;
}

extern "C" void kernel_launch(void* const* d_in, const int* in_sizes, int n_in,
                              void* d_out, int out_size, void* d_ws, size_t ws_size,
                              hipStream_t stream) {
  const float* x   = (const float*)d_in[0];
  const float* wq  = (const float*)d_in[1];
  const float* bq  = (const float*)d_in[2];
  const float* wk  = (const float*)d_in[3];
  const float* bk  = (const float*)d_in[4];
  const float* wvf = (const float*)d_in[5];
  const float* bvf = (const float*)d_in[6];
  const float* wo  = (const float*)d_in[7];
  const float* bo  = (const float*)d_in[8];
  float* out = (float*)d_out;
  char* ws = (char*)d_ws;

  USH*   wqt = (USH*)(ws);
  USH*   wkt = (USH*)(ws + 8388608);
  USH*   Qb  = (USH*)(ws + 16777216);
  USH*   Kb  = (USH*)(ws + 33554432);
  float* vw  = (float*)(ws + 50331648);
  float* wvo = (float*)(ws + 50593792);
  float* bvo = (float*)(ws + 50724864);
  float* part= (float*)(ws + 50725120);
  USH*   xbf = (USH*)(ws + 50987264);  // 16.78 MB, ends at 67,764,480

  const bool fast = (ws_size >= 67764480ull);

  k_transw<<<dim3(32, 32, 2), dim3(256), 0, stream>>>(wq, wk, wqt, wkt);
  k_wvo<<<dim3(2049), dim3(256), 0, stream>>>(wvf, bvf, wo, wvo, bvo);
  k_vw<<<dim3(512), dim3(256), 0, stream>>>(x, wvo, bvo, vw);
  if (fast) {
    k_xbf<<<dim3(4096), dim3(256), 0, stream>>>(x, xbf);
    k_gemm<true><<<dim3(16, 32, 2), dim3(256), 0, stream>>>(x, xbf, wqt, wkt, bq, bk, Qb, Kb);
  } else {
    k_gemm<false><<<dim3(16, 32, 2), dim3(256), 0, stream>>>(x, (USH*)ws, wqt, wkt, bq, bk, Qb, Kb);
  }
  k_attn<<<dim3(32, 32), dim3(256), 0, stream>>>(Qb, Kb, vw, part);
  k_final<<<dim3(16), dim3(256), 0, stream>>>(part, bo, out);
}